// Round 2
// baseline (4921.931 us; speedup 1.0000x reference)
//
#include <hip/hip_runtime.h>
#include <hip/hip_bf16.h>

typedef __hip_bfloat16 bf16;

#define NN 500000
#define EE 2000000
#define GG 256

// weight bank offsets (in floats) — all multiples of 16 floats for float4 alignment
#define WREL1 0
#define BREL1 16
#define WROOT1 32
#define WREL2 48
#define BREL2 560
#define WROOT2 592
#define WREL3 1104
#define BREL3 3152
#define WROOT3 3216
#define WRELMU 5264
#define BRELMU 9360
#define WROOTMU 9424
#define WRELLV 13520
#define BRELLV 17616
#define WROOTLV 17680
#define GNW 21776
#define GNB 21840
#define GNMS 21904

// ---- dtype-agnostic loads (flags resolved at runtime by probe_k) ----
__device__ __forceinline__ float loadF(const void* p, size_t i, int isbf) {
  if (isbf) return __bfloat162float(((const bf16*)p)[i]);
  return ((const float*)p)[i];
}
__device__ __forceinline__ int loadI(const void* p, size_t i, int is64) {
  if (is64) return (int)(((const long long*)p)[i]);
  return ((const int*)p)[i];
}

__global__ void probe_k(const void* ew, const void* ei, const void* batch,
                        int* __restrict__ flags) {
  if (threadIdx.x != 0 || blockIdx.x != 0) return;
  // float width: bf16 data has exponent byte in bits 8..15 of each 32b word
  const unsigned* u = (const unsigned*)ew;
  int hits = 0;
  for (int i = 0; i < 64; ++i) {
    unsigned b1 = (u[i] >> 8) & 0xFF;
    if (b1 >= 0x30 && b1 <= 0x3F) hits++;
  }
  flags[0] = (hits >= 32) ? 1 : 0;  // 1 => floats are bf16
  // edge_index width: int64 => odd 32b words are zero high-words
  const int* w = (const int*)ei;
  int nz = 0;
  for (int i = 1; i < 512; i += 2) nz += (w[i] != 0);
  flags[1] = (nz == 0) ? 1 : 0;  // 1 => int64
  // batch width: probe odd word indices near the tail (values ~255 if int32)
  const int* b = (const int*)batch;
  int nzb = 0;
  for (int k = 0; k < 64; ++k) nzb += (b[NN - 1 - 2 * k] != 0);
  flags[2] = (nzb == 0) ? 1 : 0;  // 1 => int64
}

struct WArg {
  const void* p[18];
  int sz[18];
  int off[18];
};

__global__ void cvt_weights(WArg a, float* __restrict__ out, const int* __restrict__ flg) {
  int fb = flg[0];
  int b = blockIdx.x;
  const void* src = a.p[b];
  float* dst = out + a.off[b];
  int n = a.sz[b];
  for (int i = threadIdx.x; i < n; i += blockDim.x)
    dst[i] = loadF(src, i, fb);
}

__global__ void seg_offsets(const void* __restrict__ batch, int* __restrict__ offs,
                            const int* __restrict__ flg) {
  int f64 = flg[2];
  int g = blockIdx.x * blockDim.x + threadIdx.x;
  if (g > GG) return;
  int lo = 0, hi = NN;
  while (lo < hi) {
    int mid = (lo + hi) >> 1;
    if (loadI(batch, mid, f64) < g) lo = mid + 1; else hi = mid;
  }
  offs[g] = lo;
}

__global__ void scatter1(const void* __restrict__ x, const void* __restrict__ ei,
                         const void* __restrict__ ew, float* __restrict__ agg,
                         const int* __restrict__ flg) {
  int fb = flg[0], fi = flg[1];
  int e = blockIdx.x * blockDim.x + threadIdx.x;
  if (e >= EE) return;
  int s = loadI(ei, e, fi);
  int d = loadI(ei, (size_t)EE + e, fi);
  float v = loadF(x, s, fb) * loadF(ew, e, fb);
  unsafeAtomicAdd(&agg[d], v);
}

__global__ void node1(const void* __restrict__ x, const float* __restrict__ agg,
                      const float* __restrict__ wb, float* __restrict__ h1,
                      const int* __restrict__ flg) {
  int fb = flg[0];
  int n = blockIdx.x * blockDim.x + threadIdx.x;
  if (n >= NN) return;
  float a = agg[n];
  float xx = loadF(x, n, fb);
  float o[16];
#pragma unroll
  for (int c = 0; c < 16; ++c) {
    float v = a * wb[WREL1 + c] + wb[BREL1 + c] + xx * wb[WROOT1 + c];
    o[c] = fmaxf(v, 0.f);
  }
  float4* dst = (float4*)(h1 + (size_t)n * 16);
#pragma unroll
  for (int j = 0; j < 4; ++j)
    dst[j] = make_float4(o[4 * j], o[4 * j + 1], o[4 * j + 2], o[4 * j + 3]);
}

template <int C>
__global__ void scatter_k(const float* __restrict__ h, const void* __restrict__ ei,
                          const void* __restrict__ ew, float* __restrict__ agg,
                          const int* __restrict__ flg) {
  int fb = flg[0], fi = flg[1];
  constexpr int C4 = C / 4;
  unsigned tid = blockIdx.x * blockDim.x + threadIdx.x;
  if (tid >= (unsigned)EE * C4) return;
  int e = tid / C4;
  int c = (tid % C4) * 4;
  int s = loadI(ei, e, fi);
  int d = loadI(ei, (size_t)EE + e, fi);
  float w = loadF(ew, e, fb);
  float4 v = *(const float4*)(h + (size_t)s * C + c);
  float* ag = agg + (size_t)d * C + c;
  unsafeAtomicAdd(ag + 0, v.x * w);
  unsafeAtomicAdd(ag + 1, v.y * w);
  unsafeAtomicAdd(ag + 2, v.z * w);
  unsafeAtomicAdd(ag + 3, v.w * w);
}

template <int CIN, int COUT, bool RELU>
__global__ void node_k(const float* __restrict__ agg, const float* __restrict__ in,
                       const float* __restrict__ wrel, const float* __restrict__ bias,
                       const float* __restrict__ wroot, float* __restrict__ out) {
  constexpr int C4 = COUT / 4;
  unsigned tid = blockIdx.x * blockDim.x + threadIdx.x;
  if (tid >= (unsigned)NN * C4) return;
  int n = tid / C4;
  int c = (tid % C4) * 4;
  float4 acc = *(const float4*)(bias + c);
  const float* ai = agg + (size_t)n * CIN;
  const float* hi = in + (size_t)n * CIN;
#pragma unroll 8
  for (int k = 0; k < CIN; ++k) {
    float a = ai[k], x = hi[k];
    float4 wr = *(const float4*)(wrel + k * COUT + c);
    float4 wo = *(const float4*)(wroot + k * COUT + c);
    acc.x += a * wr.x + x * wo.x;
    acc.y += a * wr.y + x * wo.y;
    acc.z += a * wr.z + x * wo.z;
    acc.w += a * wr.w + x * wo.w;
  }
  if (RELU) {
    acc.x = fmaxf(acc.x, 0.f);
    acc.y = fmaxf(acc.y, 0.f);
    acc.z = fmaxf(acc.z, 0.f);
    acc.w = fmaxf(acc.w, 0.f);
  }
  *(float4*)(out + (size_t)n * COUT + c) = acc;
}

__global__ void graphnorm(float* __restrict__ h, const int* __restrict__ offs,
                          const float* __restrict__ wb) {
  __shared__ float red[256];
  __shared__ float meanms[64];
  __shared__ float scale[64];
  int g = blockIdx.x;
  int s = offs[g], e = offs[g + 1];
  int len = e - s;
  if (len <= 0) return;
  long base = (long)s * 64, end = (long)e * 64;
  int t = threadIdx.x;
  int c = t & 63;

  float local = 0.f;
  for (long i = base + t; i < end; i += 256) local += h[i];
  red[t] = local;
  __syncthreads();
  if (t < 64) {
    float sum = red[t] + red[t + 64] + red[t + 128] + red[t + 192];
    meanms[t] = (sum / (float)len) * wb[GNMS + t];
  }
  __syncthreads();

  local = 0.f;
  for (long i = base + t; i < end; i += 256) {
    float sub = h[i] - meanms[c];
    local += sub * sub;
  }
  red[t] = local;
  __syncthreads();
  if (t < 64) {
    float v = (red[t] + red[t + 64] + red[t + 128] + red[t + 192]) / (float)len;
    scale[t] = wb[GNW + t] * rsqrtf(v + 1e-5f);
  }
  __syncthreads();

  for (long i = base + t; i < end; i += 256) {
    float sub = h[i] - meanms[c];
    h[i] = scale[c] * sub + wb[GNB + c];
  }
}

__device__ __forceinline__ unsigned short bfb(float f) {
  bf16 h = __float2bfloat16(f);
  union { bf16 b; unsigned short u; } cv;
  cv.b = h;
  return cv.u;
}

__global__ void final_k(const float* __restrict__ agg, const float* __restrict__ h,
                        const float* __restrict__ wb, void* __restrict__ out,
                        const int* __restrict__ flg) {
  int fb = flg[0];
  unsigned tid = blockIdx.x * blockDim.x + threadIdx.x;
  if (tid >= (unsigned)NN * 16) return;
  int n = tid >> 4;
  int c = (tid & 15) * 4;
  float4 amu = *(const float4*)(wb + BRELMU + c);
  float4 alv = *(const float4*)(wb + BRELLV + c);
  const float* ai = agg + (size_t)n * 64;
  const float* hi = h + (size_t)n * 64;
#pragma unroll 8
  for (int k = 0; k < 64; ++k) {
    float a = ai[k], x = hi[k];
    float4 wrm = *(const float4*)(wb + WRELMU + k * 64 + c);
    float4 wom = *(const float4*)(wb + WROOTMU + k * 64 + c);
    float4 wrl = *(const float4*)(wb + WRELLV + k * 64 + c);
    float4 wol = *(const float4*)(wb + WROOTLV + k * 64 + c);
    amu.x += a * wrm.x + x * wom.x;
    amu.y += a * wrm.y + x * wom.y;
    amu.z += a * wrm.z + x * wom.z;
    amu.w += a * wrm.w + x * wom.w;
    alv.x += a * wrl.x + x * wol.x;
    alv.y += a * wrl.y + x * wol.y;
    alv.z += a * wrl.z + x * wol.z;
    alv.w += a * wrl.w + x * wol.w;
  }
  if (fb) {
    unsigned short* ob = (unsigned short*)out;
    ushort4 um = make_ushort4(bfb(amu.x), bfb(amu.y), bfb(amu.z), bfb(amu.w));
    ushort4 ul = make_ushort4(bfb(alv.x), bfb(alv.y), bfb(alv.z), bfb(alv.w));
    *(ushort4*)(ob + (size_t)n * 64 + c) = um;
    *(ushort4*)(ob + (size_t)NN * 64 + (size_t)n * 64 + c) = ul;
  } else {
    float* of = (float*)out;
    *(float4*)(of + (size_t)n * 64 + c) = amu;
    *(float4*)(of + (size_t)NN * 64 + (size_t)n * 64 + c) = alv;
  }
}

extern "C" void kernel_launch(void* const* d_in, const int* in_sizes, int n_in,
                              void* d_out, int out_size, void* d_ws, size_t ws_size,
                              hipStream_t stream) {
  const void* x = d_in[0];
  const void* ei = d_in[1];
  const void* ew = d_in[2];
  const void* batch = d_in[3];

  char* ws = (char*)d_ws;
  // layout (bytes):
  //   [0,            128,000,000)  H3 / normalized h   (N*64 f32)
  //   [128,000,000,  256,000,000)  region R, time-shared:
  //        h1   = R + 0          (N*16 f32, 32 MB)
  //        agg1 = R + 32,000,000 (N f32, 2 MB)      [conv1]
  //        agg2 = R + 32,000,000 (N*16 f32, 32 MB)  [conv2]
  //        h2   = R + 64,000,000 (N*32 f32, 64 MB)
  //        agg3 = R + 0          (N*32 f32, 64 MB)  [conv3; h1 dead]
  //        agg45= R + 0          (N*64 f32, 128 MB) [conv mu/lv; h2 dead]
  //   [256,000,000, +88KB)  fp32 weight bank
  //   [256,100,000, +1028)  graph segment offsets
  //   [256,102,048, +16)    dtype flags
  float* H3 = (float*)(ws);
  char* R = ws + 128000000;
  float* h1 = (float*)(R);
  float* agg1 = (float*)(R + 32000000);
  float* agg2 = (float*)(R + 32000000);
  float* h2 = (float*)(R + 64000000);
  float* agg3 = (float*)(R);
  float* agg45 = (float*)(R);
  float* wb = (float*)(ws + 256000000);
  int* offs = (int*)(ws + 256100000);
  int* flags = (int*)(ws + 256102048);

  WArg wa;
  const int wsz[18] = {16, 16, 16, 512, 32, 512, 2048, 64, 2048,
                       4096, 64, 4096, 4096, 64, 4096, 64, 64, 64};
  const int woff[18] = {WREL1, BREL1, WROOT1, WREL2, BREL2, WROOT2,
                        WREL3, BREL3, WROOT3, WRELMU, BRELMU, WROOTMU,
                        WRELLV, BRELLV, WROOTLV, GNW, GNB, GNMS};
  for (int i = 0; i < 18; ++i) {
    wa.p[i] = d_in[4 + i];
    wa.sz[i] = wsz[i];
    wa.off[i] = woff[i];
  }

  probe_k<<<1, 64, 0, stream>>>(ew, ei, batch, flags);
  cvt_weights<<<18, 256, 0, stream>>>(wa, wb, flags);
  seg_offsets<<<2, 256, 0, stream>>>(batch, offs, flags);

  // ---- conv1: C_in=1 -> C_out=16
  hipMemsetAsync(agg1, 0, (size_t)NN * sizeof(float), stream);
  scatter1<<<(EE + 255) / 256, 256, 0, stream>>>(x, ei, ew, agg1, flags);
  node1<<<(NN + 255) / 256, 256, 0, stream>>>(x, agg1, wb, h1, flags);

  // ---- conv2: 16 -> 32
  hipMemsetAsync(agg2, 0, (size_t)NN * 16 * sizeof(float), stream);
  scatter_k<16><<<(EE * 4 + 255) / 256, 256, 0, stream>>>(h1, ei, ew, agg2, flags);
  node_k<16, 32, true><<<(NN * 8 + 255) / 256, 256, 0, stream>>>(
      agg2, h1, wb + WREL2, wb + BREL2, wb + WROOT2, h2);

  // ---- conv3: 32 -> 64
  hipMemsetAsync(agg3, 0, (size_t)NN * 32 * sizeof(float), stream);
  scatter_k<32><<<(EE * 8 + 255) / 256, 256, 0, stream>>>(h2, ei, ew, agg3, flags);
  node_k<32, 64, true><<<(NN * 16 + 255) / 256, 256, 0, stream>>>(
      agg3, h2, wb + WREL3, wb + BREL3, wb + WROOT3, H3);

  // ---- GraphNorm (in place on H3)
  graphnorm<<<GG, 256, 0, stream>>>(H3, offs, wb);

  // ---- conv mu + conv logvar (shared edge aggregation)
  hipMemsetAsync(agg45, 0, (size_t)NN * 64 * sizeof(float), stream);
  scatter_k<64><<<(EE * 16 + 255) / 256, 256, 0, stream>>>(H3, ei, ew, agg45, flags);
  final_k<<<(NN * 16 + 255) / 256, 256, 0, stream>>>(agg45, H3, wb, d_out, flags);
}

// Round 3
// 1427.992 us; speedup vs baseline: 3.4467x; 3.4467x over previous
//
#include <hip/hip_runtime.h>
#include <hip/hip_bf16.h>

typedef __hip_bfloat16 bf16;
typedef unsigned short u16;
typedef unsigned int u32;

#define NN 500000
#define EE 2000000
#define GG 256
#define NB_SCAN 489  // ceil(500000/1024)

// weight bank offsets (floats)
#define WREL1 0
#define BREL1 16
#define WROOT1 32
#define WREL2 48
#define BREL2 560
#define WROOT2 592
#define WREL3 1104
#define BREL3 3152
#define WROOT3 3216
#define WRELMU 5264
#define BRELMU 9360
#define WROOTMU 9424
#define WRELLV 13520
#define BRELLV 17616
#define WROOTLV 17680
#define GNW 21776
#define GNB 21840
#define GNMS 21904

__device__ __forceinline__ float b2f(u16 u) {
  union { u32 i; float f; } cv; cv.i = ((u32)u) << 16; return cv.f;
}
__device__ __forceinline__ u16 f2b(float f) {
  union { bf16 b; u16 u; } cv; cv.b = __float2bfloat16(f); return cv.u;
}
__device__ __forceinline__ float loadF(const void* p, size_t i, int isbf) {
  if (isbf) return b2f(((const u16*)p)[i]);
  return ((const float*)p)[i];
}
__device__ __forceinline__ int loadI(const void* p, size_t i, int is64) {
  if (is64) return (int)(((const long long*)p)[i]);
  return ((const int*)p)[i];
}

__global__ void probe_k(const void* ew, const void* ei, const void* batch,
                        int* __restrict__ flags) {
  if (threadIdx.x != 0 || blockIdx.x != 0) return;
  const u32* u = (const u32*)ew;
  int hits = 0;
  for (int i = 0; i < 64; ++i) {
    u32 b1 = (u[i] >> 8) & 0xFF;
    if (b1 >= 0x30 && b1 <= 0x3F) hits++;
  }
  flags[0] = (hits >= 32) ? 1 : 0;  // floats are bf16
  const int* w = (const int*)ei;
  int nz = 0;
  for (int i = 1; i < 512; i += 2) nz += (w[i] != 0);
  flags[1] = (nz == 0) ? 1 : 0;  // edge_index int64
  const int* b = (const int*)batch;
  int nzb = 0;
  for (int k = 0; k < 64; ++k) nzb += (b[NN - 1 - 2 * k] != 0);
  flags[2] = (nzb == 0) ? 1 : 0;  // batch int64
}

struct WArg { const void* p[18]; int sz[18]; int off[18]; };

__global__ void cvt_weights(WArg a, float* __restrict__ out, const int* __restrict__ flg) {
  int fb = flg[0];
  int b = blockIdx.x;
  const void* src = a.p[b];
  float* dst = out + a.off[b];
  int n = a.sz[b];
  for (int i = threadIdx.x; i < n; i += blockDim.x) dst[i] = loadF(src, i, fb);
}

__global__ void seg_offsets(const void* __restrict__ batch, int* __restrict__ goffs,
                            const int* __restrict__ flg) {
  int f64 = flg[2];
  int g = blockIdx.x * blockDim.x + threadIdx.x;
  if (g > GG) return;
  int lo = 0, hi = NN;
  while (lo < hi) {
    int mid = (lo + hi) >> 1;
    if (loadI(batch, mid, f64) < g) lo = mid + 1; else hi = mid;
  }
  goffs[g] = lo;
}

// ---------------- CSR build ----------------
__global__ void hist_k(const void* __restrict__ ei, int* __restrict__ counts,
                       const int* __restrict__ flg) {
  int fi = flg[1];
  int e = blockIdx.x * blockDim.x + threadIdx.x;
  if (e >= EE) return;
  int d = loadI(ei, (size_t)EE + e, fi);
  atomicAdd(&counts[d], 1);
}

__global__ void scan1_k(const int* __restrict__ counts, int* __restrict__ chunkscan,
                        int* __restrict__ bsum) {
  __shared__ int lds[256];
  int b = blockIdx.x, t = threadIdx.x;
  int base = b * 1024 + t * 4;
  int c0 = 0, c1 = 0, c2 = 0, c3 = 0;
  if (base + 3 < NN) {
    int4 c = *(const int4*)(counts + base);
    c0 = c.x; c1 = c.y; c2 = c.z; c3 = c.w;
  } else {
    if (base + 0 < NN) c0 = counts[base + 0];
    if (base + 1 < NN) c1 = counts[base + 1];
    if (base + 2 < NN) c2 = counts[base + 2];
    if (base + 3 < NN) c3 = counts[base + 3];
  }
  int s0 = c0, s1 = s0 + c1, s2 = s1 + c2, s3 = s2 + c3;
  lds[t] = s3;
  __syncthreads();
  for (int off = 1; off < 256; off <<= 1) {
    int v = lds[t];
    if (t >= off) v += lds[t - off];
    __syncthreads();
    lds[t] = v;
    __syncthreads();
  }
  int excl = (t > 0) ? lds[t - 1] : 0;
  if (base + 0 < NN) chunkscan[base + 0] = excl + s0;
  if (base + 1 < NN) chunkscan[base + 1] = excl + s1;
  if (base + 2 < NN) chunkscan[base + 2] = excl + s2;
  if (base + 3 < NN) chunkscan[base + 3] = excl + s3;
  if (t == 255) bsum[b] = lds[255];
}

__global__ void scan2_k(int* __restrict__ bsum) {
  if (threadIdx.x != 0 || blockIdx.x != 0) return;
  int run = 0;
  for (int b = 0; b < NB_SCAN; ++b) { int t = bsum[b]; bsum[b] = run; run += t; }
}

__global__ void scan3_k(const int* __restrict__ chunkscan, const int* __restrict__ bsum,
                        const int* __restrict__ counts, int* __restrict__ offs,
                        int* __restrict__ cursor) {
  int i = blockIdx.x * blockDim.x + threadIdx.x;
  if (i >= NN) return;
  int pref = chunkscan[i] + bsum[i >> 10];
  offs[i + 1] = pref;
  cursor[i] = pref - counts[i];
  if (i == 0) offs[0] = 0;
}

__global__ void fill_k(const void* __restrict__ ei, const void* __restrict__ ew,
                       int* __restrict__ cursor, int* __restrict__ col,
                       float* __restrict__ wgt, const int* __restrict__ flg) {
  int fi = flg[1], fb = flg[0];
  int e = blockIdx.x * blockDim.x + threadIdx.x;
  if (e >= EE) return;
  int s = loadI(ei, e, fi);
  int d = loadI(ei, (size_t)EE + e, fi);
  float w = loadF(ew, e, fb);
  int pos = atomicAdd(&cursor[d], 1);
  col[pos] = s;
  wgt[pos] = w;
}

// ---------------- conv1 (fused agg + transform, C_in=1 -> 16) ----------------
__global__ void conv1_k(const void* __restrict__ x, const int* __restrict__ col,
                        const float* __restrict__ wgt, const int* __restrict__ offs,
                        const float* __restrict__ wb, u16* __restrict__ h1,
                        const int* __restrict__ flg) {
  int fb = flg[0];
  int n = blockIdx.x * blockDim.x + threadIdx.x;
  if (n >= NN) return;
  float acc = 0.f;
  int j1 = offs[n + 1];
  for (int j = offs[n]; j < j1; ++j) acc += wgt[j] * loadF(x, col[j], fb);
  float xx = loadF(x, n, fb);
  u32 pk[8];
#pragma unroll
  for (int p = 0; p < 8; ++p) {
    float v0 = fmaxf(acc * wb[WREL1 + 2 * p] + wb[BREL1 + 2 * p] + xx * wb[WROOT1 + 2 * p], 0.f);
    float v1 = fmaxf(acc * wb[WREL1 + 2 * p + 1] + wb[BREL1 + 2 * p + 1] + xx * wb[WROOT1 + 2 * p + 1], 0.f);
    pk[p] = (u32)f2b(v0) | ((u32)f2b(v1) << 16);
  }
  uint4* dst = (uint4*)(h1 + (size_t)n * 16);
  dst[0] = make_uint4(pk[0], pk[1], pk[2], pk[3]);
  dst[1] = make_uint4(pk[4], pk[5], pk[6], pk[7]);
}

// ---------------- gather aggregation: C/2 lanes per node, 2 ch/lane ----------------
template <int C>
__global__ void agg_g(const u16* __restrict__ h, const int* __restrict__ col,
                      const float* __restrict__ wgt, const int* __restrict__ offs,
                      float* __restrict__ agg) {
  constexpr int L = C / 2;
  size_t gid = (size_t)blockIdx.x * blockDim.x + threadIdx.x;
  int node = (int)(gid / L);
  int c2 = (int)(gid % L);
  if (node >= NN) return;
  int j1 = offs[node + 1];
  float a0 = 0.f, a1 = 0.f;
  for (int j = offs[node]; j < j1; ++j) {
    int s = col[j];
    float w = wgt[j];
    u32 p = *(const u32*)(h + (size_t)s * C + c2 * 2);
    a0 += w * b2f((u16)(p & 0xFFFF));
    a1 += w * b2f((u16)(p >> 16));
  }
  *(float2*)(agg + (size_t)node * C + c2 * 2) = make_float2(a0, a1);
}

// ---------------- node transform: agg(f32) + h(bf16) -> out(bf16) ----------------
template <int CIN, int COUT>
__global__ void node_k(const float* __restrict__ agg, const u16* __restrict__ in,
                       const float* __restrict__ wrel, const float* __restrict__ bias,
                       const float* __restrict__ wroot, u16* __restrict__ out) {
  constexpr int C4 = COUT / 4;
  size_t tid = (size_t)blockIdx.x * blockDim.x + threadIdx.x;
  if (tid >= (size_t)NN * C4) return;
  int n = (int)(tid / C4);
  int c = (int)(tid % C4) * 4;
  float4 acc = *(const float4*)(bias + c);
  const float* ai = agg + (size_t)n * CIN;
  const u16* hi = in + (size_t)n * CIN;
#pragma unroll 8
  for (int k = 0; k < CIN; ++k) {
    float a = ai[k], x = b2f(hi[k]);
    float4 wr = *(const float4*)(wrel + k * COUT + c);
    float4 wo = *(const float4*)(wroot + k * COUT + c);
    acc.x += a * wr.x + x * wo.x;
    acc.y += a * wr.y + x * wo.y;
    acc.z += a * wr.z + x * wo.z;
    acc.w += a * wr.w + x * wo.w;
  }
  u32 p0 = (u32)f2b(fmaxf(acc.x, 0.f)) | ((u32)f2b(fmaxf(acc.y, 0.f)) << 16);
  u32 p1 = (u32)f2b(fmaxf(acc.z, 0.f)) | ((u32)f2b(fmaxf(acc.w, 0.f)) << 16);
  *(uint2*)(out + (size_t)n * COUT + c) = make_uint2(p0, p1);
}

// ---------------- GraphNorm (bf16 in place), 1024 threads/block ----------------
__global__ void graphnorm(u16* __restrict__ h, const int* __restrict__ goffs,
                          const float* __restrict__ wb) {
  __shared__ float red[1024];
  __shared__ float meanms[64];
  __shared__ float scale[64];
  int g = blockIdx.x;
  int s = goffs[g], e = goffs[g + 1];
  int len = e - s;
  if (len <= 0) return;
  long base = (long)s * 64, end = (long)e * 64;
  int t = threadIdx.x;
  int c = t & 63;

  float local = 0.f;
  for (long i = base + t; i < end; i += 1024) local += b2f(h[i]);
  red[t] = local;
  __syncthreads();
  if (t < 64) {
    float sum = 0.f;
#pragma unroll
    for (int j = 0; j < 16; ++j) sum += red[t + 64 * j];
    meanms[t] = (sum / (float)len) * wb[GNMS + t];
  }
  __syncthreads();

  local = 0.f;
  for (long i = base + t; i < end; i += 1024) {
    float sub = b2f(h[i]) - meanms[c];
    local += sub * sub;
  }
  red[t] = local;
  __syncthreads();
  if (t < 64) {
    float v = 0.f;
#pragma unroll
    for (int j = 0; j < 16; ++j) v += red[t + 64 * j];
    scale[t] = wb[GNW + t] * rsqrtf(v / (float)len + 1e-5f);
  }
  __syncthreads();

  for (long i = base + t; i < end; i += 1024) {
    float sub = b2f(h[i]) - meanms[c];
    h[i] = f2b(scale[c] * sub + wb[GNB + c]);
  }
}

// ---------------- final: mu + logvar, 4-node register blocking ----------------
__global__ void final_k(const float* __restrict__ agg, const u16* __restrict__ h,
                        const float* __restrict__ wb, void* __restrict__ out,
                        const int* __restrict__ flg) {
  int fb = flg[0];
  size_t tid = (size_t)blockIdx.x * blockDim.x + threadIdx.x;
  int grp = (int)(tid >> 4);          // 4-node group
  if (grp >= NN / 4) return;
  int c = (int)(tid & 15) * 4;
  int n0 = grp * 4;
  float4 amu[4], alv[4];
  float4 bmu = *(const float4*)(wb + BRELMU + c);
  float4 blv = *(const float4*)(wb + BRELLV + c);
#pragma unroll
  for (int i = 0; i < 4; ++i) { amu[i] = bmu; alv[i] = blv; }
  const float* ai = agg + (size_t)n0 * 64;
  const u16* hi = h + (size_t)n0 * 64;
#pragma unroll 4
  for (int k = 0; k < 64; ++k) {
    float4 wrm = *(const float4*)(wb + WRELMU + k * 64 + c);
    float4 wom = *(const float4*)(wb + WROOTMU + k * 64 + c);
    float4 wrl = *(const float4*)(wb + WRELLV + k * 64 + c);
    float4 wol = *(const float4*)(wb + WROOTLV + k * 64 + c);
#pragma unroll
    for (int i = 0; i < 4; ++i) {
      float a = ai[i * 64 + k];
      float x = b2f(hi[i * 64 + k]);
      amu[i].x += a * wrm.x + x * wom.x;
      amu[i].y += a * wrm.y + x * wom.y;
      amu[i].z += a * wrm.z + x * wom.z;
      amu[i].w += a * wrm.w + x * wom.w;
      alv[i].x += a * wrl.x + x * wol.x;
      alv[i].y += a * wrl.y + x * wol.y;
      alv[i].z += a * wrl.z + x * wol.z;
      alv[i].w += a * wrl.w + x * wol.w;
    }
  }
  if (fb) {
    u16* ob = (u16*)out;
#pragma unroll
    for (int i = 0; i < 4; ++i) {
      u32 m0 = (u32)f2b(amu[i].x) | ((u32)f2b(amu[i].y) << 16);
      u32 m1 = (u32)f2b(amu[i].z) | ((u32)f2b(amu[i].w) << 16);
      u32 l0 = (u32)f2b(alv[i].x) | ((u32)f2b(alv[i].y) << 16);
      u32 l1 = (u32)f2b(alv[i].z) | ((u32)f2b(alv[i].w) << 16);
      *(uint2*)(ob + (size_t)(n0 + i) * 64 + c) = make_uint2(m0, m1);
      *(uint2*)(ob + (size_t)NN * 64 + (size_t)(n0 + i) * 64 + c) = make_uint2(l0, l1);
    }
  } else {
    float* of = (float*)out;
#pragma unroll
    for (int i = 0; i < 4; ++i) {
      *(float4*)(of + (size_t)(n0 + i) * 64 + c) = amu[i];
      *(float4*)(of + (size_t)NN * 64 + (size_t)(n0 + i) * 64 + c) = alv[i];
    }
  }
}

extern "C" void kernel_launch(void* const* d_in, const int* in_sizes, int n_in,
                              void* d_out, int out_size, void* d_ws, size_t ws_size,
                              hipStream_t stream) {
  const void* x = d_in[0];
  const void* ei = d_in[1];
  const void* ew = d_in[2];
  const void* batch = d_in[3];

  char* ws = (char*)d_ws;
  // Layout (bytes, decimal MB):
  //  A [0, 64e6):        H3 bf16 (N*64*2)
  //  B [64e6, 88e6):     CSR + misc (persistent):
  //     col   @64e6 (8e6)   wgt @72e6 (8e6)   offs @80e6 (2.000004e6)
  //     counts@83e6 (2e6)   cursor @85e6 (2e6) bsum @87.0e6 (~2KB)
  //     wb    @87.1e6 (88KB) goffs @87.25e6 (1028B) flags @87.3e6
  //  C [88e6, 256e6) time-shared:
  //     chunkscan @C+0 (2e6, CSR build only)
  //     h1  bf16 @C+0      [88e6,104e6)
  //     agg2 f32 @C+16e6   [104e6,136e6)
  //     h2  bf16 @C+104e6  [192e6,256e6)
  //     agg3 f32 @C+0      [88e6,152e6)   (h1,agg2 dead)
  //     agg45 f32 @C+0     [88e6,216e6)   (h2 dead)
  u16* H3 = (u16*)(ws);
  int* col = (int*)(ws + 64000000);
  float* wgt = (float*)(ws + 72000000);
  int* offs = (int*)(ws + 80000000);
  int* counts = (int*)(ws + 83000000);
  int* cursor = (int*)(ws + 85000000);
  int* bsum = (int*)(ws + 87000000);
  float* wb = (float*)(ws + 87100000);
  int* goffs = (int*)(ws + 87250000);
  int* flags = (int*)(ws + 87300000);
  char* C = ws + 88000000;
  int* chunkscan = (int*)(C);
  u16* h1 = (u16*)(C);
  float* agg2 = (float*)(C + 16000000);
  u16* h2 = (u16*)(C + 104000000);
  float* agg3 = (float*)(C);
  float* agg45 = (float*)(C);

  WArg wa;
  const int wsz[18] = {16, 16, 16, 512, 32, 512, 2048, 64, 2048,
                       4096, 64, 4096, 4096, 64, 4096, 64, 64, 64};
  const int woff[18] = {WREL1, BREL1, WROOT1, WREL2, BREL2, WROOT2,
                        WREL3, BREL3, WROOT3, WRELMU, BRELMU, WROOTMU,
                        WRELLV, BRELLV, WROOTLV, GNW, GNB, GNMS};
  for (int i = 0; i < 18; ++i) { wa.p[i] = d_in[4 + i]; wa.sz[i] = wsz[i]; wa.off[i] = woff[i]; }

  probe_k<<<1, 64, 0, stream>>>(ew, ei, batch, flags);
  cvt_weights<<<18, 256, 0, stream>>>(wa, wb, flags);
  seg_offsets<<<2, 256, 0, stream>>>(batch, goffs, flags);

  // CSR build
  hipMemsetAsync(counts, 0, (size_t)NN * sizeof(int), stream);
  hist_k<<<(EE + 255) / 256, 256, 0, stream>>>(ei, counts, flags);
  scan1_k<<<NB_SCAN, 256, 0, stream>>>(counts, chunkscan, bsum);
  scan2_k<<<1, 64, 0, stream>>>(bsum);
  scan3_k<<<(NN + 255) / 256, 256, 0, stream>>>(chunkscan, bsum, counts, offs, cursor);
  fill_k<<<(EE + 255) / 256, 256, 0, stream>>>(ei, ew, cursor, col, wgt, flags);

  // conv1: 1 -> 16
  conv1_k<<<(NN + 255) / 256, 256, 0, stream>>>(x, col, wgt, offs, wb, h1, flags);

  // conv2: 16 -> 32
  agg_g<16><<<(NN * 8 + 255) / 256, 256, 0, stream>>>(h1, col, wgt, offs, agg2);
  node_k<16, 32><<<(NN * 8 + 255) / 256, 256, 0, stream>>>(
      agg2, h1, wb + WREL2, wb + BREL2, wb + WROOT2, h2);

  // conv3: 32 -> 64
  agg_g<32><<<(NN * 16 + 255) / 256, 256, 0, stream>>>(h2, col, wgt, offs, agg3);
  node_k<32, 64><<<(NN * 16 + 255) / 256, 256, 0, stream>>>(
      agg3, h2, wb + WREL3, wb + BREL3, wb + WROOT3, H3);

  // GraphNorm in place on H3 (bf16)
  graphnorm<<<GG, 1024, 0, stream>>>(H3, goffs, wb);

  // mu + logvar (shared aggregation)
  agg_g<64><<<(NN * 32 + 255) / 256, 256, 0, stream>>>(H3, col, wgt, offs, agg45);
  final_k<<<(NN * 4 + 255) / 256, 256, 0, stream>>>(agg45, H3, wb, d_out, flags);
}

// Round 4
// 783.667 us; speedup vs baseline: 6.2806x; 1.8222x over previous
//
#include <hip/hip_runtime.h>
#include <hip/hip_bf16.h>

typedef __hip_bfloat16 bf16;
typedef unsigned short u16;
typedef unsigned int u32;
typedef __attribute__((ext_vector_type(8))) short s16x8;
typedef __attribute__((ext_vector_type(4))) float f32x4;

#define NN 500000
#define EE 2000000
#define GG 256
#define NB_SCAN 489  // ceil(500000/1024)

// weight bank offsets (floats)
#define WREL1 0
#define BREL1 16
#define WROOT1 32
#define WREL2 48
#define BREL2 560
#define WROOT2 592
#define WREL3 1104
#define BREL3 3152
#define WROOT3 3216
#define WRELMU 5264
#define BRELMU 9360
#define WROOTMU 9424
#define WRELLV 13520
#define BRELLV 17616
#define WROOTLV 17680
#define GNW 21776
#define GNB 21840
#define GNMS 21904

__device__ __forceinline__ float b2f(u16 u) {
  union { u32 i; float f; } cv; cv.i = ((u32)u) << 16; return cv.f;
}
__device__ __forceinline__ u16 f2b(float f) {
  union { bf16 b; u16 u; } cv; cv.b = __float2bfloat16(f); return cv.u;
}
__device__ __forceinline__ float loadF(const void* p, size_t i, int isbf) {
  if (isbf) return b2f(((const u16*)p)[i]);
  return ((const float*)p)[i];
}
__device__ __forceinline__ int loadI(const void* p, size_t i, int is64) {
  if (is64) return (int)(((const long long*)p)[i]);
  return ((const int*)p)[i];
}

__global__ void probe_k(const void* ew, const void* ei, const void* batch,
                        int* __restrict__ flags) {
  if (threadIdx.x != 0 || blockIdx.x != 0) return;
  const u32* u = (const u32*)ew;
  int hits = 0;
  for (int i = 0; i < 64; ++i) {
    u32 b1 = (u[i] >> 8) & 0xFF;
    if (b1 >= 0x30 && b1 <= 0x3F) hits++;
  }
  flags[0] = (hits >= 32) ? 1 : 0;  // floats are bf16
  const int* w = (const int*)ei;
  int nz = 0;
  for (int i = 1; i < 512; i += 2) nz += (w[i] != 0);
  flags[1] = (nz == 0) ? 1 : 0;  // edge_index int64
  const int* b = (const int*)batch;
  int nzb = 0;
  for (int k = 0; k < 64; ++k) nzb += (b[NN - 1 - 2 * k] != 0);
  flags[2] = (nzb == 0) ? 1 : 0;  // batch int64
}

struct WArg { const void* p[18]; int sz[18]; int off[18]; };

__global__ void cvt_weights(WArg a, float* __restrict__ out, const int* __restrict__ flg) {
  int fb = flg[0];
  int b = blockIdx.x;
  const void* src = a.p[b];
  float* dst = out + a.off[b];
  int n = a.sz[b];
  for (int i = threadIdx.x; i < n; i += blockDim.x) dst[i] = loadF(src, i, fb);
}

// pack weights into MFMA B-fragment order (+ bias vectors), per layer
__global__ void pack_w(const float* __restrict__ wb, u16* __restrict__ wp2,
                       u16* __restrict__ wp3, u16* __restrict__ wpF,
                       float* __restrict__ b2, float* __restrict__ b3,
                       float* __restrict__ bF) {
  int L = blockIdx.x;
  int K = (L == 0) ? 32 : (L == 1) ? 64 : 128;
  int COUT = K;
  int KS = K / 32;
  u16* wp = (L == 0) ? wp2 : (L == 1) ? wp3 : wpF;
  int total = K * COUT;
  for (int idx = threadIdx.x; idx < total; idx += blockDim.x) {
    int j = idx & 7;
    int l = (idx >> 3) & 63;
    int rest = idx >> 9;
    int s = rest % KS;
    int t = rest / KS;
    int k = s * 32 + (l >> 4) * 8 + j;
    int c = t * 16 + (l & 15);
    float v;
    if (L == 0) {
      v = (k < 16) ? wb[WREL2 + k * 32 + c] : wb[WROOT2 + (k - 16) * 32 + c];
    } else if (L == 1) {
      v = (k < 32) ? wb[WREL3 + k * 64 + c] : wb[WROOT3 + (k - 32) * 64 + c];
    } else {
      int cc = c & 63;
      int base;
      if (k < 64) base = (c < 64) ? WRELMU : WRELLV;
      else base = (c < 64) ? WROOTMU : WROOTLV;
      int kk = (k < 64) ? k : (k - 64);
      v = wb[base + kk * 64 + cc];
    }
    wp[idx] = f2b(v);
  }
  for (int c = threadIdx.x; c < COUT; c += blockDim.x) {
    if (L == 0) b2[c] = wb[BREL2 + c];
    else if (L == 1) b3[c] = wb[BREL3 + c];
    else bF[c] = (c < 64) ? wb[BRELMU + c] : wb[BRELLV + (c - 64)];
  }
}

__global__ void seg_offsets(const void* __restrict__ batch, int* __restrict__ goffs,
                            const int* __restrict__ flg) {
  int f64 = flg[2];
  int g = blockIdx.x * blockDim.x + threadIdx.x;
  if (g > GG) return;
  int lo = 0, hi = NN;
  while (lo < hi) {
    int mid = (lo + hi) >> 1;
    if (loadI(batch, mid, f64) < g) lo = mid + 1; else hi = mid;
  }
  goffs[g] = lo;
}

// ---------------- CSR build ----------------
__global__ void hist_k(const void* __restrict__ ei, int* __restrict__ counts,
                       const int* __restrict__ flg) {
  int fi = flg[1];
  int e = blockIdx.x * blockDim.x + threadIdx.x;
  if (e >= EE) return;
  int d = loadI(ei, (size_t)EE + e, fi);
  atomicAdd(&counts[d], 1);
}

__global__ void scan1_k(const int* __restrict__ counts, int* __restrict__ chunkscan,
                        int* __restrict__ bsum) {
  __shared__ int lds[256];
  int b = blockIdx.x, t = threadIdx.x;
  int base = b * 1024 + t * 4;
  int c0 = 0, c1 = 0, c2 = 0, c3 = 0;
  if (base + 3 < NN) {
    int4 c = *(const int4*)(counts + base);
    c0 = c.x; c1 = c.y; c2 = c.z; c3 = c.w;
  } else {
    if (base + 0 < NN) c0 = counts[base + 0];
    if (base + 1 < NN) c1 = counts[base + 1];
    if (base + 2 < NN) c2 = counts[base + 2];
    if (base + 3 < NN) c3 = counts[base + 3];
  }
  int s0 = c0, s1 = s0 + c1, s2 = s1 + c2, s3 = s2 + c3;
  lds[t] = s3;
  __syncthreads();
  for (int off = 1; off < 256; off <<= 1) {
    int v = lds[t];
    if (t >= off) v += lds[t - off];
    __syncthreads();
    lds[t] = v;
    __syncthreads();
  }
  int excl = (t > 0) ? lds[t - 1] : 0;
  if (base + 0 < NN) chunkscan[base + 0] = excl + s0;
  if (base + 1 < NN) chunkscan[base + 1] = excl + s1;
  if (base + 2 < NN) chunkscan[base + 2] = excl + s2;
  if (base + 3 < NN) chunkscan[base + 3] = excl + s3;
  if (t == 255) bsum[b] = lds[255];
}

__global__ void scan2_k(int* __restrict__ bsum) {
  __shared__ int lds[512];
  int t = threadIdx.x;
  int v = (t < NB_SCAN) ? bsum[t] : 0;
  lds[t] = v;
  __syncthreads();
  for (int off = 1; off < 512; off <<= 1) {
    int x = lds[t];
    if (t >= off) x += lds[t - off];
    __syncthreads();
    lds[t] = x;
    __syncthreads();
  }
  if (t < NB_SCAN) bsum[t] = lds[t] - v;  // exclusive
}

__global__ void scan3_k(const int* __restrict__ chunkscan, const int* __restrict__ bsum,
                        const int* __restrict__ counts, int* __restrict__ offs,
                        int* __restrict__ cursor) {
  int i = blockIdx.x * blockDim.x + threadIdx.x;
  if (i >= NN) return;
  int pref = chunkscan[i] + bsum[i >> 10];
  offs[i + 1] = pref;
  cursor[i] = pref - counts[i];
  if (i == 0) offs[0] = 0;
}

__global__ void fill_k(const void* __restrict__ ei, const void* __restrict__ ew,
                       int* __restrict__ cursor, int2* __restrict__ cw,
                       const int* __restrict__ flg) {
  int fi = flg[1], fb = flg[0];
  int e = blockIdx.x * blockDim.x + threadIdx.x;
  if (e >= EE) return;
  int s = loadI(ei, e, fi);
  int d = loadI(ei, (size_t)EE + e, fi);
  float w = loadF(ew, e, fb);
  int pos = atomicAdd(&cursor[d], 1);
  cw[pos] = make_int2(s, __float_as_int(w));
}

// ---------------- conv1 (fused agg + transform, C_in=1 -> 16) ----------------
__global__ void conv1_k(const void* __restrict__ x, const int2* __restrict__ cw,
                        const int* __restrict__ offs, const float* __restrict__ wb,
                        u16* __restrict__ h1, const int* __restrict__ flg) {
  int fb = flg[0];
  int n = blockIdx.x * blockDim.x + threadIdx.x;
  if (n >= NN) return;
  float acc = 0.f;
  int j1 = offs[n + 1];
  for (int j = offs[n]; j < j1; ++j) {
    int2 p = cw[j];
    acc += __int_as_float(p.y) * loadF(x, p.x, fb);
  }
  float xx = loadF(x, n, fb);
  u32 pk[8];
#pragma unroll
  for (int p = 0; p < 8; ++p) {
    float v0 = fmaxf(acc * wb[WREL1 + 2 * p] + wb[BREL1 + 2 * p] + xx * wb[WROOT1 + 2 * p], 0.f);
    float v1 = fmaxf(acc * wb[WREL1 + 2 * p + 1] + wb[BREL1 + 2 * p + 1] + xx * wb[WROOT1 + 2 * p + 1], 0.f);
    pk[p] = (u32)f2b(v0) | ((u32)f2b(v1) << 16);
  }
  uint4* dst = (uint4*)(h1 + (size_t)n * 16);
  dst[0] = make_uint4(pk[0], pk[1], pk[2], pk[3]);
  dst[1] = make_uint4(pk[4], pk[5], pk[6], pk[7]);
}

// ---------------- gather aggregation -> bf16 agg ----------------
template <int C>
__global__ void agg_g(const u16* __restrict__ h, const int2* __restrict__ cw,
                      const int* __restrict__ offs, u16* __restrict__ agg) {
  constexpr int L = C / 2;
  size_t gid = (size_t)blockIdx.x * blockDim.x + threadIdx.x;
  int node = (int)(gid / L);
  int c2 = (int)(gid % L);
  if (node >= NN) return;
  int j1 = offs[node + 1];
  float a0 = 0.f, a1 = 0.f;
  for (int j = offs[node]; j < j1; ++j) {
    int2 p = cw[j];
    float w = __int_as_float(p.y);
    u32 hv = *(const u32*)(h + (size_t)p.x * C + c2 * 2);
    a0 += w * b2f((u16)(hv & 0xFFFF));
    a1 += w * b2f((u16)(hv >> 16));
  }
  u32 o = (u32)f2b(a0) | ((u32)f2b(a1) << 16);
  *(u32*)(agg + (size_t)node * C + c2 * 2) = o;
}

// ---------------- MFMA node transform ----------------
// out[n, 0:COUT] = relu?( [aggX | hX][n, 0:K] @ Wpack + bias )
// FINAL: COUT=128 -> mu = cols 0:64 (out + n*64), lv = cols 64:128 (out + NN*64 + n*64)
template <int K, int COUT, bool RELU, bool FINAL>
__global__ __launch_bounds__(256) void mfma_node(
    const u16* __restrict__ aggX, const u16* __restrict__ hX,
    const u16* __restrict__ wpack, const float* __restrict__ bias,
    void* __restrict__ outp, const int* __restrict__ flg) {
  constexpr int KS = K / 32, CT = COUT / 16, HALF = K / 2;
  __shared__ u16 wl[K * COUT];
  __shared__ float bl[COUT];
  int tid = threadIdx.x;
  for (int i = tid; i < K * COUT / 8; i += 256)
    ((uint4*)wl)[i] = ((const uint4*)wpack)[i];
  for (int i = tid; i < COUT; i += 256) bl[i] = bias[i];
  __syncthreads();
  int fb = FINAL ? flg[0] : 1;
  int lane = tid & 63, wave = tid >> 6;
  int q = lane & 15;       // A-row / C-col within tile
  int kgrp = lane >> 4;    // k-group for A, row-group for C
  const int ntiles = NN / 16;  // 500000 % 16 == 0
  for (int tile = blockIdx.x * 4 + wave; tile < ntiles; tile += gridDim.x * 4) {
    int n0 = tile * 16;
    s16x8 a[KS];
#pragma unroll
    for (int s = 0; s < KS; ++s) {
      int kb = s * 32 + kgrp * 8;
      const u16* src = (kb < HALF)
          ? (aggX + (size_t)(n0 + q) * HALF + kb)
          : (hX + (size_t)(n0 + q) * HALF + (kb - HALF));
      a[s] = *(const s16x8*)src;
    }
    f32x4 acc[CT];
#pragma unroll
    for (int t = 0; t < CT; ++t) {
      float bv = bl[t * 16 + q];
      acc[t] = (f32x4){bv, bv, bv, bv};
    }
#pragma unroll
    for (int s = 0; s < KS; ++s) {
#pragma unroll
      for (int t = 0; t < CT; ++t) {
        s16x8 b = *(const s16x8*)(wl + ((size_t)(t * KS + s) * 64 + lane) * 8);
        acc[t] = __builtin_amdgcn_mfma_f32_16x16x32_bf16(a[s], b, acc[t], 0, 0, 0);
      }
    }
    if (!FINAL) {
      u16* out = (u16*)outp;
#pragma unroll
      for (int t = 0; t < CT; ++t) {
        int c = t * 16 + q;
#pragma unroll
        for (int r = 0; r < 4; ++r) {
          float v = acc[t][r];
          if (RELU) v = fmaxf(v, 0.f);
          out[(size_t)(n0 + kgrp * 4 + r) * COUT + c] = f2b(v);
        }
      }
    } else {
#pragma unroll
      for (int t = 0; t < CT; ++t) {
        int c = t * 16 + q;
#pragma unroll
        for (int r = 0; r < 4; ++r) {
          int n = n0 + kgrp * 4 + r;
          float v = acc[t][r];
          size_t addr = (t < 4) ? ((size_t)n * 64 + c)
                                : ((size_t)NN * 64 + (size_t)n * 64 + (c - 64));
          if (fb) ((u16*)outp)[addr] = f2b(v);
          else ((float*)outp)[addr] = v;
        }
      }
    }
  }
}

// ---------------- GraphNorm (bf16 in place) ----------------
__global__ void graphnorm(u16* __restrict__ h, const int* __restrict__ goffs,
                          const float* __restrict__ wb) {
  __shared__ float red[1024];
  __shared__ float meanms[64];
  __shared__ float scale[64];
  int g = blockIdx.x;
  int s = goffs[g], e = goffs[g + 1];
  int len = e - s;
  if (len <= 0) return;
  long base = (long)s * 64, end = (long)e * 64;
  int t = threadIdx.x;
  int c = t & 63;

  float local = 0.f;
  for (long i = base + t; i < end; i += 1024) local += b2f(h[i]);
  red[t] = local;
  __syncthreads();
  if (t < 64) {
    float sum = 0.f;
#pragma unroll
    for (int j = 0; j < 16; ++j) sum += red[t + 64 * j];
    meanms[t] = (sum / (float)len) * wb[GNMS + t];
  }
  __syncthreads();

  local = 0.f;
  for (long i = base + t; i < end; i += 1024) {
    float sub = b2f(h[i]) - meanms[c];
    local += sub * sub;
  }
  red[t] = local;
  __syncthreads();
  if (t < 64) {
    float v = 0.f;
#pragma unroll
    for (int j = 0; j < 16; ++j) v += red[t + 64 * j];
    scale[t] = wb[GNW + t] * rsqrtf(v / (float)len + 1e-5f);
  }
  __syncthreads();

  for (long i = base + t; i < end; i += 1024) {
    float sub = b2f(h[i]) - meanms[c];
    h[i] = f2b(scale[c] * sub + wb[GNB + c]);
  }
}

extern "C" void kernel_launch(void* const* d_in, const int* in_sizes, int n_in,
                              void* d_out, int out_size, void* d_ws, size_t ws_size,
                              hipStream_t stream) {
  const void* x = d_in[0];
  const void* ei = d_in[1];
  const void* ew = d_in[2];
  const void* batch = d_in[3];

  char* ws = (char*)d_ws;
  // Layout (bytes):
  //  H3      [0, 64e6)        bf16 N*64
  //  cw      [64e6, 80e6)     int2 E (col, wgt-bits)
  //  offs    [80e6, +2.000004e6)
  //  counts  [83e6, +2e6)  cursor [85e6, +2e6)  bsum [87e6, +4KB)
  //  wb      [87.1e6, +88KB)  goffs [87.25e6, +1028B)  flags [87.3e6, +16B)
  //  wp2     [87.35e6, +2KB)  wp3 [87.4e6, +8KB)  wpF [87.45e6, +32KB)
  //  bias2   [87.5e6) bias3 [87.51e6) biasF [87.52e6)
  //  C = [88e6, 256e6), time-shared:
  //    chunkscan @C (2MB, CSR build only)
  //    h1    bf16 N*16 @C+0     [88e6, 104e6)
  //    aggX2 bf16 N*16 @C+16e6  [104e6, 120e6)
  //    h2    bf16 N*32 @C+32e6  [120e6, 152e6)
  //    aggX3 bf16 N*32 @C+64e6  [152e6, 184e6)  (h1/aggX2 dead)
  //    aggX45 bf16 N*64 @C+96e6 [184e6, 248e6)  (h2/aggX3 dead)
  u16* H3 = (u16*)(ws);
  int2* cw = (int2*)(ws + 64000000);
  int* offs = (int*)(ws + 80000000);
  int* counts = (int*)(ws + 83000000);
  int* cursor = (int*)(ws + 85000000);
  int* bsum = (int*)(ws + 87000000);
  float* wb = (float*)(ws + 87100000);
  int* goffs = (int*)(ws + 87250000);
  int* flags = (int*)(ws + 87300000);
  u16* wp2 = (u16*)(ws + 87350000);
  u16* wp3 = (u16*)(ws + 87400000);
  u16* wpF = (u16*)(ws + 87450000);
  float* bias2 = (float*)(ws + 87500000);
  float* bias3 = (float*)(ws + 87510000);
  float* biasF = (float*)(ws + 87520000);
  char* C = ws + 88000000;
  int* chunkscan = (int*)(C);
  u16* h1 = (u16*)(C);
  u16* aggX2 = (u16*)(C + 16000000);
  u16* h2 = (u16*)(C + 32000000);
  u16* aggX3 = (u16*)(C + 64000000);
  u16* aggX45 = (u16*)(C + 96000000);

  WArg wa;
  const int wsz[18] = {16, 16, 16, 512, 32, 512, 2048, 64, 2048,
                       4096, 64, 4096, 4096, 64, 4096, 64, 64, 64};
  const int woff[18] = {WREL1, BREL1, WROOT1, WREL2, BREL2, WROOT2,
                        WREL3, BREL3, WROOT3, WRELMU, BRELMU, WROOTMU,
                        WRELLV, BRELLV, WROOTLV, GNW, GNB, GNMS};
  for (int i = 0; i < 18; ++i) { wa.p[i] = d_in[4 + i]; wa.sz[i] = wsz[i]; wa.off[i] = woff[i]; }

  probe_k<<<1, 64, 0, stream>>>(ew, ei, batch, flags);
  cvt_weights<<<18, 256, 0, stream>>>(wa, wb, flags);
  pack_w<<<3, 256, 0, stream>>>(wb, wp2, wp3, wpF, bias2, bias3, biasF);
  seg_offsets<<<2, 256, 0, stream>>>(batch, goffs, flags);

  // CSR build
  hipMemsetAsync(counts, 0, (size_t)NN * sizeof(int), stream);
  hist_k<<<(EE + 255) / 256, 256, 0, stream>>>(ei, counts, flags);
  scan1_k<<<NB_SCAN, 256, 0, stream>>>(counts, chunkscan, bsum);
  scan2_k<<<1, 512, 0, stream>>>(bsum);
  scan3_k<<<(NN + 255) / 256, 256, 0, stream>>>(chunkscan, bsum, counts, offs, cursor);
  fill_k<<<(EE + 255) / 256, 256, 0, stream>>>(ei, ew, cursor, cw, flags);

  // conv1: 1 -> 16
  conv1_k<<<(NN + 255) / 256, 256, 0, stream>>>(x, cw, offs, wb, h1, flags);

  // conv2: 16 -> 32 (K=32)
  agg_g<16><<<(NN * 8 + 255) / 256, 256, 0, stream>>>(h1, cw, offs, aggX2);
  mfma_node<32, 32, true, false><<<1024, 256, 0, stream>>>(
      aggX2, h1, wp2, bias2, h2, flags);

  // conv3: 32 -> 64 (K=64)
  agg_g<32><<<(NN * 16 + 255) / 256, 256, 0, stream>>>(h2, cw, offs, aggX3);
  mfma_node<64, 64, true, false><<<1024, 256, 0, stream>>>(
      aggX3, h2, wp3, bias3, H3, flags);

  // GraphNorm in place on H3 (bf16)
  graphnorm<<<GG, 1024, 0, stream>>>(H3, goffs, wb);

  // mu + logvar (shared aggregation, K=128, COUT=128)
  agg_g<64><<<(NN * 32 + 255) / 256, 256, 0, stream>>>(H3, cw, offs, aggX45);
  mfma_node<128, 128, false, true><<<2048, 256, 0, stream>>>(
      aggX45, H3, wpF, biasF, d_out, flags);
}

// Round 5
// 717.288 us; speedup vs baseline: 6.8619x; 1.0925x over previous
//
#include <hip/hip_runtime.h>
#include <hip/hip_bf16.h>

typedef __hip_bfloat16 bf16;
typedef unsigned short u16;
typedef unsigned int u32;
typedef __attribute__((ext_vector_type(8))) short s16x8;
typedef __attribute__((ext_vector_type(4))) float f32x4;

#define NN 500000
#define EE 2000000
#define GG 256
#define NB_SCAN 489  // ceil(500000/1024)

// weight bank offsets (floats)
#define WREL1 0
#define BREL1 16
#define WROOT1 32
#define WREL2 48
#define BREL2 560
#define WROOT2 592
#define WREL3 1104
#define BREL3 3152
#define WROOT3 3216
#define WRELMU 5264
#define BRELMU 9360
#define WROOTMU 9424
#define WRELLV 13520
#define BRELLV 17616
#define WROOTLV 17680
#define GNW 21776
#define GNB 21840
#define GNMS 21904

__device__ __forceinline__ float b2f(u16 u) {
  union { u32 i; float f; } cv; cv.i = ((u32)u) << 16; return cv.f;
}
__device__ __forceinline__ u16 f2b(float f) {
  union { bf16 b; u16 u; } cv; cv.b = __float2bfloat16(f); return cv.u;
}
__device__ __forceinline__ float loadF(const void* p, size_t i, int isbf) {
  if (isbf) return b2f(((const u16*)p)[i]);
  return ((const float*)p)[i];
}
__device__ __forceinline__ int loadI(const void* p, size_t i, int is64) {
  if (is64) return (int)(((const long long*)p)[i]);
  return ((const int*)p)[i];
}

__global__ void probe_k(const void* ew, const void* ei, const void* batch,
                        int* __restrict__ flags) {
  if (threadIdx.x != 0 || blockIdx.x != 0) return;
  const u32* u = (const u32*)ew;
  int hits = 0;
  for (int i = 0; i < 64; ++i) {
    u32 b1 = (u[i] >> 8) & 0xFF;
    if (b1 >= 0x30 && b1 <= 0x3F) hits++;
  }
  flags[0] = (hits >= 32) ? 1 : 0;  // floats are bf16
  const int* w = (const int*)ei;
  int nz = 0;
  for (int i = 1; i < 512; i += 2) nz += (w[i] != 0);
  flags[1] = (nz == 0) ? 1 : 0;  // edge_index int64
  const int* b = (const int*)batch;
  int nzb = 0;
  for (int k = 0; k < 64; ++k) nzb += (b[NN - 1 - 2 * k] != 0);
  flags[2] = (nzb == 0) ? 1 : 0;  // batch int64
}

struct WArg { const void* p[18]; int sz[18]; int off[18]; };

__global__ void cvt_weights(WArg a, float* __restrict__ out, const int* __restrict__ flg) {
  int fb = flg[0];
  int b = blockIdx.x;
  const void* src = a.p[b];
  float* dst = out + a.off[b];
  int n = a.sz[b];
  for (int i = threadIdx.x; i < n; i += blockDim.x) dst[i] = loadF(src, i, fb);
}

// pack weights into MFMA B-fragment order (+ bias vectors), per layer
__global__ void pack_w(const float* __restrict__ wb, u16* __restrict__ wp2,
                       u16* __restrict__ wp3, u16* __restrict__ wpF,
                       float* __restrict__ b2, float* __restrict__ b3,
                       float* __restrict__ bF) {
  int L = blockIdx.x;
  int K = (L == 0) ? 32 : (L == 1) ? 64 : 128;
  int COUT = K;
  int KS = K / 32;
  u16* wp = (L == 0) ? wp2 : (L == 1) ? wp3 : wpF;
  int total = K * COUT;
  for (int idx = threadIdx.x; idx < total; idx += blockDim.x) {
    int j = idx & 7;
    int l = (idx >> 3) & 63;
    int rest = idx >> 9;
    int s = rest % KS;
    int t = rest / KS;
    int k = s * 32 + (l >> 4) * 8 + j;
    int c = t * 16 + (l & 15);
    float v;
    if (L == 0) {
      v = (k < 16) ? wb[WREL2 + k * 32 + c] : wb[WROOT2 + (k - 16) * 32 + c];
    } else if (L == 1) {
      v = (k < 32) ? wb[WREL3 + k * 64 + c] : wb[WROOT3 + (k - 32) * 64 + c];
    } else {
      int cc = c & 63;
      int base;
      if (k < 64) base = (c < 64) ? WRELMU : WRELLV;
      else base = (c < 64) ? WROOTMU : WROOTLV;
      int kk = (k < 64) ? k : (k - 64);
      v = wb[base + kk * 64 + cc];
    }
    wp[idx] = f2b(v);
  }
  for (int c = threadIdx.x; c < COUT; c += blockDim.x) {
    if (L == 0) b2[c] = wb[BREL2 + c];
    else if (L == 1) b3[c] = wb[BREL3 + c];
    else bF[c] = (c < 64) ? wb[BRELMU + c] : wb[BRELLV + (c - 64)];
  }
}

__global__ void seg_offsets(const void* __restrict__ batch, int* __restrict__ goffs,
                            const int* __restrict__ flg) {
  int f64 = flg[2];
  int g = blockIdx.x * blockDim.x + threadIdx.x;
  if (g > GG) return;
  int lo = 0, hi = NN;
  while (lo < hi) {
    int mid = (lo + hi) >> 1;
    if (loadI(batch, mid, f64) < g) lo = mid + 1; else hi = mid;
  }
  goffs[g] = lo;
}

// ---------------- CSR build ----------------
__global__ void hist_k(const void* __restrict__ ei, int* __restrict__ counts,
                       const int* __restrict__ flg) {
  int fi = flg[1];
  int e = blockIdx.x * blockDim.x + threadIdx.x;
  if (e >= EE) return;
  int d = loadI(ei, (size_t)EE + e, fi);
  atomicAdd(&counts[d], 1);
}

__global__ void scan1_k(const int* __restrict__ counts, int* __restrict__ chunkscan,
                        int* __restrict__ bsum) {
  __shared__ int lds[256];
  int b = blockIdx.x, t = threadIdx.x;
  int base = b * 1024 + t * 4;
  int c0 = 0, c1 = 0, c2 = 0, c3 = 0;
  if (base + 3 < NN) {
    int4 c = *(const int4*)(counts + base);
    c0 = c.x; c1 = c.y; c2 = c.z; c3 = c.w;
  } else {
    if (base + 0 < NN) c0 = counts[base + 0];
    if (base + 1 < NN) c1 = counts[base + 1];
    if (base + 2 < NN) c2 = counts[base + 2];
    if (base + 3 < NN) c3 = counts[base + 3];
  }
  int s0 = c0, s1 = s0 + c1, s2 = s1 + c2, s3 = s2 + c3;
  lds[t] = s3;
  __syncthreads();
  for (int off = 1; off < 256; off <<= 1) {
    int v = lds[t];
    if (t >= off) v += lds[t - off];
    __syncthreads();
    lds[t] = v;
    __syncthreads();
  }
  int excl = (t > 0) ? lds[t - 1] : 0;
  if (base + 0 < NN) chunkscan[base + 0] = excl + s0;
  if (base + 1 < NN) chunkscan[base + 1] = excl + s1;
  if (base + 2 < NN) chunkscan[base + 2] = excl + s2;
  if (base + 3 < NN) chunkscan[base + 3] = excl + s3;
  if (t == 255) bsum[b] = lds[255];
}

__global__ void scan2_k(int* __restrict__ bsum) {
  __shared__ int lds[512];
  int t = threadIdx.x;
  int v = (t < NB_SCAN) ? bsum[t] : 0;
  lds[t] = v;
  __syncthreads();
  for (int off = 1; off < 512; off <<= 1) {
    int x = lds[t];
    if (t >= off) x += lds[t - off];
    __syncthreads();
    lds[t] = x;
    __syncthreads();
  }
  if (t < NB_SCAN) bsum[t] = lds[t] - v;  // exclusive
}

__global__ void scan3_k(const int* __restrict__ chunkscan, const int* __restrict__ bsum,
                        const int* __restrict__ counts, int* __restrict__ offs,
                        int* __restrict__ cursor) {
  int i = blockIdx.x * blockDim.x + threadIdx.x;
  if (i >= NN) return;
  int pref = chunkscan[i] + bsum[i >> 10];
  offs[i + 1] = pref;
  cursor[i] = pref - counts[i];
  if (i == 0) offs[0] = 0;
}

__global__ void fill_k(const void* __restrict__ ei, const void* __restrict__ ew,
                       int* __restrict__ cursor, int2* __restrict__ cw,
                       const int* __restrict__ flg) {
  int fi = flg[1], fb = flg[0];
  int e = blockIdx.x * blockDim.x + threadIdx.x;
  if (e >= EE) return;
  int s = loadI(ei, e, fi);
  int d = loadI(ei, (size_t)EE + e, fi);
  float w = loadF(ew, e, fb);
  int pos = atomicAdd(&cursor[d], 1);
  cw[pos] = make_int2(s, __float_as_int(w));
}

// ---------------- conv1 (fused agg + transform, C_in=1 -> 16) ----------------
__global__ void conv1_k(const void* __restrict__ x, const int2* __restrict__ cw,
                        const int* __restrict__ offs, const float* __restrict__ wb,
                        u16* __restrict__ h1, const int* __restrict__ flg) {
  int fb = flg[0];
  int n = blockIdx.x * blockDim.x + threadIdx.x;
  if (n >= NN) return;
  float acc = 0.f;
  int j1 = offs[n + 1];
  for (int j = offs[n]; j < j1; ++j) {
    int2 p = cw[j];
    acc += __int_as_float(p.y) * loadF(x, p.x, fb);
  }
  float xx = loadF(x, n, fb);
  u32 pk[8];
#pragma unroll
  for (int p = 0; p < 8; ++p) {
    float v0 = fmaxf(acc * wb[WREL1 + 2 * p] + wb[BREL1 + 2 * p] + xx * wb[WROOT1 + 2 * p], 0.f);
    float v1 = fmaxf(acc * wb[WREL1 + 2 * p + 1] + wb[BREL1 + 2 * p + 1] + xx * wb[WROOT1 + 2 * p + 1], 0.f);
    pk[p] = (u32)f2b(v0) | ((u32)f2b(v1) << 16);
  }
  uint4* dst = (uint4*)(h1 + (size_t)n * 16);
  dst[0] = make_uint4(pk[0], pk[1], pk[2], pk[3]);
  dst[1] = make_uint4(pk[4], pk[5], pk[6], pk[7]);
}

// ---------------- fused gather + MFMA node transform ----------------
// X[n, 0:K] = [ agg(hin)[n, 0:CIN] | hin[n, 0:CIN] ],  out = relu?(X @ Wpack + bias)
// A-fragment: lane (q,kgrp) holds X[n0+q][k], k = s*32 + kgrp*8 + j.
// k < CIN  -> aggregated (gathered in-register); k >= CIN -> root (direct load).
template <int K, int COUT, bool RELU, bool FINAL>
__global__ __launch_bounds__(256) void fused_conv(
    const u16* __restrict__ hin, const int2* __restrict__ cw,
    const int* __restrict__ offs, const u16* __restrict__ wpack,
    const float* __restrict__ bias, void* __restrict__ outp,
    const int* __restrict__ flg) {
  constexpr int KS = K / 32, CT = COUT / 16, CIN = K / 2;
  __shared__ u16 wl[K * COUT];
  __shared__ float bl[COUT];
  int tid = threadIdx.x;
  for (int i = tid; i < K * COUT / 8; i += 256)
    ((uint4*)wl)[i] = ((const uint4*)wpack)[i];
  for (int i = tid; i < COUT; i += 256) bl[i] = bias[i];
  __syncthreads();
  int fb = FINAL ? flg[0] : 1;
  int lane = tid & 63, wave = tid >> 6;
  int q = lane & 15, kgrp = lane >> 4;
  const int ntiles = NN / 16;
  for (int tile = blockIdx.x * 4 + wave; tile < ntiles; tile += gridDim.x * 4) {
    int n0 = tile * 16;
    int n = n0 + q;
    // ---- gather-aggregate into this lane's fragment channels
    float gacc[KS][8];
#pragma unroll
    for (int s = 0; s < KS; ++s)
#pragma unroll
      for (int jj = 0; jj < 8; ++jj) gacc[s][jj] = 0.f;
    int jb = offs[n], je = offs[n + 1];
    for (int j = jb; j < je; ++j) {
      int2 p = cw[j];
      float w = __int_as_float(p.y);
#pragma unroll
      for (int s = 0; s < KS; ++s) {
        int k0 = s * 32 + kgrp * 8;
        if (k0 < CIN) {
          s16x8 v = *(const s16x8*)(hin + (size_t)p.x * CIN + k0);
#pragma unroll
          for (int jj = 0; jj < 8; ++jj)
            gacc[s][jj] += w * b2f((u16)v[jj]);
        }
      }
    }
    // ---- build A fragments
    s16x8 a[KS];
#pragma unroll
    for (int s = 0; s < KS; ++s) {
      int k0 = s * 32 + kgrp * 8;
      if (k0 < CIN) {
        s16x8 t;
#pragma unroll
        for (int jj = 0; jj < 8; ++jj) t[jj] = (short)f2b(gacc[s][jj]);
        a[s] = t;
      } else {
        a[s] = *(const s16x8*)(hin + (size_t)n * CIN + (k0 - CIN));
      }
    }
    // ---- MFMA
    f32x4 acc[CT];
#pragma unroll
    for (int t = 0; t < CT; ++t) {
      float bv = bl[t * 16 + q];
      acc[t] = (f32x4){bv, bv, bv, bv};
    }
#pragma unroll
    for (int s = 0; s < KS; ++s) {
#pragma unroll
      for (int t = 0; t < CT; ++t) {
        s16x8 b = *(const s16x8*)(wl + ((size_t)(t * KS + s) * 64 + lane) * 8);
        acc[t] = __builtin_amdgcn_mfma_f32_16x16x32_bf16(a[s], b, acc[t], 0, 0, 0);
      }
    }
    // ---- epilogue
    if (!FINAL) {
      u16* out = (u16*)outp;
#pragma unroll
      for (int t = 0; t < CT; ++t) {
        int c = t * 16 + q;
#pragma unroll
        for (int r = 0; r < 4; ++r) {
          float v = acc[t][r];
          if (RELU) v = fmaxf(v, 0.f);
          out[(size_t)(n0 + kgrp * 4 + r) * COUT + c] = f2b(v);
        }
      }
    } else {
#pragma unroll
      for (int t = 0; t < CT; ++t) {
        int c = t * 16 + q;
#pragma unroll
        for (int r = 0; r < 4; ++r) {
          int nn = n0 + kgrp * 4 + r;
          float v = acc[t][r];
          size_t addr = (t < 4) ? ((size_t)nn * 64 + c)
                                : ((size_t)NN * 64 + (size_t)nn * 64 + (c - 64));
          if (fb) ((u16*)outp)[addr] = f2b(v);
          else ((float*)outp)[addr] = v;
        }
      }
    }
  }
}

// ---------------- GraphNorm, 2-pass (sum+sumsq fused), H3 -> H3n ----------------
__global__ void graphnorm2(const u16* __restrict__ h, u16* __restrict__ hn,
                           const int* __restrict__ goffs, const float* __restrict__ wb) {
  __shared__ float red[1024];
  __shared__ float red2[1024];
  __shared__ float Ax[64];
  __shared__ float Bx[64];
  int g = blockIdx.x;
  int s = goffs[g], e = goffs[g + 1];
  int len = e - s;
  if (len <= 0) return;
  long base = (long)s * 64, end = (long)e * 64;
  int t = threadIdx.x;
  int c = t & 63;

  float ls = 0.f, lq = 0.f;
  for (long i = base + t; i < end; i += 1024) {
    float v = b2f(h[i]);
    ls += v; lq += v * v;
  }
  red[t] = ls; red2[t] = lq;
  __syncthreads();
  if (t < 64) {
    float S = 0.f, Q = 0.f;
#pragma unroll
    for (int j = 0; j < 16; ++j) { S += red[t + 64 * j]; Q += red2[t + 64 * j]; }
    float mean = S / (float)len;
    float ex2 = Q / (float)len;
    float mms = mean * wb[GNMS + t];
    float var = ex2 - 2.f * mms * mean + mms * mms;
    float a = wb[GNW + t] * rsqrtf(var + 1e-5f);
    Ax[t] = a;
    Bx[t] = wb[GNB + t] - mms * a;
  }
  __syncthreads();
  for (long i = base + t; i < end; i += 1024)
    hn[i] = f2b(b2f(h[i]) * Ax[c] + Bx[c]);
}

extern "C" void kernel_launch(void* const* d_in, const int* in_sizes, int n_in,
                              void* d_out, int out_size, void* d_ws, size_t ws_size,
                              hipStream_t stream) {
  const void* x = d_in[0];
  const void* ei = d_in[1];
  const void* ew = d_in[2];
  const void* batch = d_in[3];

  char* ws = (char*)d_ws;
  // Layout (bytes):
  //  H3      [0, 64e6)        bf16 N*64 (conv3 output, pre-norm)
  //  cw      [64e6, 80e6)     int2 E (col, wgt-bits)
  //  offs    [80e6, +2.000004e6)
  //  counts  [83e6, +2e6)  cursor [85e6, +2e6)  bsum [87e6, +4KB)
  //  wb      [87.1e6, +88KB)  goffs [87.25e6, +1028B)  flags [87.3e6, +16B)
  //  wp2     [87.35e6, +2KB)  wp3 [87.4e6, +8KB)  wpF [87.45e6, +32KB)
  //  bias2   [87.5e6) bias3 [87.51e6) biasF [87.52e6)
  //  C = [88e6, 256e6), time-shared:
  //    chunkscan @C (2MB, CSR build only)
  //    h1   bf16 N*16 @C+0     [88e6, 104e6)
  //    h2   bf16 N*32 @C+32e6  [120e6, 152e6)
  //    H3n  bf16 N*64 @C+96e6  [184e6, 248e6)  (normalized)
  u16* H3 = (u16*)(ws);
  int2* cw = (int2*)(ws + 64000000);
  int* offs = (int*)(ws + 80000000);
  int* counts = (int*)(ws + 83000000);
  int* cursor = (int*)(ws + 85000000);
  int* bsum = (int*)(ws + 87000000);
  float* wb = (float*)(ws + 87100000);
  int* goffs = (int*)(ws + 87250000);
  int* flags = (int*)(ws + 87300000);
  u16* wp2 = (u16*)(ws + 87350000);
  u16* wp3 = (u16*)(ws + 87400000);
  u16* wpF = (u16*)(ws + 87450000);
  float* bias2 = (float*)(ws + 87500000);
  float* bias3 = (float*)(ws + 87510000);
  float* biasF = (float*)(ws + 87520000);
  char* C = ws + 88000000;
  int* chunkscan = (int*)(C);
  u16* h1 = (u16*)(C);
  u16* h2 = (u16*)(C + 32000000);
  u16* H3n = (u16*)(C + 96000000);

  WArg wa;
  const int wsz[18] = {16, 16, 16, 512, 32, 512, 2048, 64, 2048,
                       4096, 64, 4096, 4096, 64, 4096, 64, 64, 64};
  const int woff[18] = {WREL1, BREL1, WROOT1, WREL2, BREL2, WROOT2,
                        WREL3, BREL3, WROOT3, WRELMU, BRELMU, WROOTMU,
                        WRELLV, BRELLV, WROOTLV, GNW, GNB, GNMS};
  for (int i = 0; i < 18; ++i) { wa.p[i] = d_in[4 + i]; wa.sz[i] = wsz[i]; wa.off[i] = woff[i]; }

  probe_k<<<1, 64, 0, stream>>>(ew, ei, batch, flags);
  cvt_weights<<<18, 256, 0, stream>>>(wa, wb, flags);
  pack_w<<<3, 256, 0, stream>>>(wb, wp2, wp3, wpF, bias2, bias3, biasF);
  seg_offsets<<<2, 256, 0, stream>>>(batch, goffs, flags);

  // CSR build
  hipMemsetAsync(counts, 0, (size_t)NN * sizeof(int), stream);
  hist_k<<<(EE + 255) / 256, 256, 0, stream>>>(ei, counts, flags);
  scan1_k<<<NB_SCAN, 256, 0, stream>>>(counts, chunkscan, bsum);
  scan2_k<<<1, 512, 0, stream>>>(bsum);
  scan3_k<<<(NN + 255) / 256, 256, 0, stream>>>(chunkscan, bsum, counts, offs, cursor);
  fill_k<<<(EE + 255) / 256, 256, 0, stream>>>(ei, ew, cursor, cw, flags);

  // conv1: 1 -> 16
  conv1_k<<<(NN + 255) / 256, 256, 0, stream>>>(x, cw, offs, wb, h1, flags);

  // conv2: 16 -> 32 (K=32), gather fused
  fused_conv<32, 32, true, false><<<2048, 256, 0, stream>>>(
      h1, cw, offs, wp2, bias2, h2, flags);

  // conv3: 32 -> 64 (K=64), gather fused
  fused_conv<64, 64, true, false><<<2048, 256, 0, stream>>>(
      h2, cw, offs, wp3, bias3, H3, flags);

  // GraphNorm: H3 -> H3n (2-pass)
  graphnorm2<<<GG, 1024, 0, stream>>>(H3, H3n, goffs, wb);

  // mu + logvar (K=128, COUT=128), gather fused, reads normalized H3n
  fused_conv<128, 128, false, true><<<2048, 256, 0, stream>>>(
      H3n, cw, offs, wpF, biasF, d_out, flags);
}